// Round 7
// baseline (150.919 us; speedup 1.0000x reference)
//
#include <hip/hip_runtime.h>

#define LOG100 4.605170185988091f
#define LOG2E  1.4426950408889634f

typedef _Float16 half8 __attribute__((ext_vector_type(8)));
typedef float f32x4 __attribute__((ext_vector_type(4)));

// ---- bias pack pre-kernel: biasP[h][kv/2][q] = fp16pair(bias[h][q][2kp], bias[h][q][2kp+1]) * LOG2E
__global__ __launch_bounds__(256) void bias_pack(const float* __restrict__ bias,
                                                 unsigned* __restrict__ biasP) {
  __shared__ float tile[32][33];
  const int head = blockIdx.z;
  const int m0 = blockIdx.x * 32;  // kv
  const int n0 = blockIdx.y * 32;  // q
  const float* src = bias + head * 65536;
  unsigned* dst = biasP + head * 32768;
  const int tx = threadIdx.x, ty = threadIdx.y;  // (32,8)
#pragma unroll
  for (int i = ty; i < 32; i += 8) tile[i][tx] = src[(n0 + i) * 256 + m0 + tx];
  __syncthreads();
#pragma unroll
  for (int j = ty; j < 16; j += 8) {
    const float lo = tile[tx][2 * j] * LOG2E;
    const float hi = tile[tx][2 * j + 1] * LOG2E;
    dst[(m0 / 2 + j) * 256 + n0 + tx] =
        __builtin_bit_cast(unsigned, __builtin_amdgcn_cvt_pkrtz(lo, hi));
  }
}

// ---- main attention kernel -------------------------------------------------
// block = (b,h), 1024 threads = 16 waves; wave wv owns q rows [wv*16, wv*16+16)
// 16x16x32 MFMA everywhere; PV uses a permuted contraction index so the S^T
// C-layout feeds the PV B-frag directly (no cross-lane exchange).
template <bool USE_BT>
__global__ __launch_bounds__(1024, 8) void attn_kernel(
    const float* __restrict__ q, const float* __restrict__ k, const float* __restrict__ v,
    const float* __restrict__ logit_scale, const float* __restrict__ bias,
    const unsigned* __restrict__ biasP, float* __restrict__ out) {
  __shared__ __align__(16) char smem[65536];
  char* KnB = smem;          // Kn: [256 kv][64 d] fp16, 128B rows, byte ^= (row&7)<<4
  char* VtB = smem + 32768;  // Vt: [64 d][256 kv'] fp16 (kv' = permuted), 512B rows, byte ^= (d&31)<<4

  const int tid = threadIdx.x;
  const int wv = tid >> 6;    // 0..15
  const int lane = tid & 63;
  const int q16 = lane & 15;  // q col within wave tile
  const int g = lane >> 4;    // 0..3 lane group
  const int head = blockIdx.x;
  const int b = blockIdx.y;

  const long base = ((long)(b * 8 + head)) * (256 * 64);
  const float* qp = q + base;
  const float* kp = k + base;
  const float* vp = v + base;

  const float scale2 = __expf(fminf(logit_scale[head], LOG100)) * LOG2E;
  const int qglob = wv * 16 + q16;

  // ---- Q B-frags (16x16x32): qfrag[dk][j] = Qn[qglob][32*dk + 8*g + j] ----
  half8 qfrag[2];
  {
    float qf[2][8];
    float ssq = 0.f;
#pragma unroll
    for (int dk = 0; dk < 2; ++dk) {
      const float4 x0 = *(const float4*)(qp + qglob * 64 + dk * 32 + g * 8);
      const float4 x1 = *(const float4*)(qp + qglob * 64 + dk * 32 + g * 8 + 4);
      qf[dk][0] = x0.x; qf[dk][1] = x0.y; qf[dk][2] = x0.z; qf[dk][3] = x0.w;
      qf[dk][4] = x1.x; qf[dk][5] = x1.y; qf[dk][6] = x1.z; qf[dk][7] = x1.w;
      ssq += x0.x * x0.x + x0.y * x0.y + x0.z * x0.z + x0.w * x0.w;
      ssq += x1.x * x1.x + x1.y * x1.y + x1.z * x1.z + x1.w * x1.w;
    }
    ssq += __shfl_xor(ssq, 16);
    ssq += __shfl_xor(ssq, 32);
    const float qinv = rsqrtf(fmaxf(ssq, 1e-24f));
#pragma unroll
    for (int dk = 0; dk < 2; ++dk)
#pragma unroll
      for (int j = 0; j < 8; ++j) qfrag[dk][j] = (_Float16)(qf[dk][j] * qinv);
  }

  // ---- stage K, L2-normalized, fp16, swizzled (1024 threads: 4 iters x 64 rows) ----
  {
    const int row_in = tid >> 4;  // 0..63
    const int seg = tid & 15;     // 16 segs * 4 floats = 64 d
#pragma unroll
    for (int it = 0; it < 4; ++it) {
      const int row = it * 64 + row_in;
      const float4 a = *(const float4*)(kp + row * 64 + seg * 4);
      float ss = a.x * a.x + a.y * a.y + a.z * a.z + a.w * a.w;
      ss += __shfl_xor(ss, 1);
      ss += __shfl_xor(ss, 2);
      ss += __shfl_xor(ss, 4);
      ss += __shfl_xor(ss, 8);
      const float inv = rsqrtf(fmaxf(ss, 1e-24f));
      union { _Float16 hh[4]; uint2 u; } pk4;
      pk4.hh[0] = (_Float16)(a.x * inv);
      pk4.hh[1] = (_Float16)(a.y * inv);
      pk4.hh[2] = (_Float16)(a.z * inv);
      pk4.hh[3] = (_Float16)(a.w * inv);
      *(uint2*)(KnB + row * 128 + ((seg * 8) ^ ((row & 7) << 4))) = pk4.u;
    }
  }

  // ---- stage V transposed+permuted: Vt[d][kv'], in-register 4x4 transpose ----
  // kv' within each 32-chunk: kv = c*32 + kvt*16 + g*4 + reg  ->  col = c*32 + g*8 + kvt*4 + reg
  {
    const int r = g;      // 0..3
    const int sx = q16;   // 0..15
#pragma unroll
    for (int it = 0; it < 4; ++it) {
      const int kv0 = (wv * 4 + it) * 4;  // 0..252, multiple of 4
      float4 a = *(const float4*)(vp + (kv0 + r) * 64 + sx * 4);
      // transpose 4x4 across lanes {sx, sx+16, sx+32, sx+48}
      float e1 = (r & 1) ? a.x : a.y;
      float g1 = __shfl_xor(e1, 16);
      float e2 = (r & 1) ? a.z : a.w;
      float g2 = __shfl_xor(e2, 16);
      if (r & 1) { a.x = g1; a.z = g2; } else { a.y = g1; a.w = g2; }
      float e3 = (r & 2) ? a.x : a.z;
      float g3 = __shfl_xor(e3, 32);
      float e4 = (r & 2) ? a.y : a.w;
      float g4 = __shfl_xor(e4, 32);
      if (r & 2) { a.x = g3; a.y = g4; } else { a.z = g3; a.w = g4; }
      // lane holds V[kv0+0..3][d], d = 4*sx + r
      const int d = 4 * sx + r;
      // permuted column for this 4-group (kv0..kv0+3 share c,kvt,gk):
      const int col0 = (kv0 & ~31) + (((kv0 >> 2) & 3) << 3) + (((kv0 >> 4) & 1) << 2);
      union { _Float16 hh[4]; uint2 u; } pk4;
      pk4.hh[0] = (_Float16)a.x;
      pk4.hh[1] = (_Float16)a.y;
      pk4.hh[2] = (_Float16)a.z;
      pk4.hh[3] = (_Float16)a.w;
      *(uint2*)(VtB + d * 512 + ((col0 * 2) ^ ((d & 31) << 4))) = pk4.u;
    }
  }

  __syncthreads();

  // ---- kv loop: 8 chunks of 32 ----
  f32x4 o[4] = {};  // O^T: o[dt] -> col q = q16, row d = 16*dt + 4*g + reg
  float m = -1.0e30f, lsum = 0.f;  // log2 domain

  const unsigned* bP = USE_BT ? (biasP + head * 32768 + qglob) : nullptr;
  const float* bF = USE_BT ? nullptr : (bias + head * 65536 + qglob * 256);

  for (int c = 0; c < 8; ++c) {
    // bias preload: packed pairs; bw[kvt*2+p] covers kv = c*32 + kvt*16 + g*4 + 2p + {0,1}
    unsigned bw[4];
    float bvf[8];
    if (USE_BT) {
#pragma unroll
      for (int kvt = 0; kvt < 2; ++kvt)
#pragma unroll
        for (int p = 0; p < 2; ++p) bw[kvt * 2 + p] = bP[(c * 16 + kvt * 8 + g * 2 + p) * 256];
    } else {
#pragma unroll
      for (int i = 0; i < 8; ++i)
        bvf[i] = bF[c * 32 + (i >> 2) * 16 + g * 4 + (i & 3)] * LOG2E;
    }

    // QK^T (16x16x32): S^T tiles kvt=0,1; A = K rows (kv = c*32 + 16*kvt + q16)
    const int rk0 = c * 32 + q16;
    const char* kb0 = KnB + rk0 * 128;
    const char* kb1 = KnB + (rk0 + 16) * 128;
    const int sw = (rk0 & 7) << 4;  // (rk0+16)&7 == rk0&7
    f32x4 s0 = {}, s1 = {};
#pragma unroll
    for (int dk = 0; dk < 2; ++dk) {
      const half8 kf0 = *(const half8*)(kb0 + ((g * 16 + dk * 64) ^ sw));
      s0 = __builtin_amdgcn_mfma_f32_16x16x32_f16(kf0, qfrag[dk], s0, 0, 0, 0);
      const half8 kf1 = *(const half8*)(kb1 + ((g * 16 + dk * 64) ^ sw));
      s1 = __builtin_amdgcn_mfma_f32_16x16x32_f16(kf1, qfrag[dk], s1, 0, 0, 0);
    }

    // scale + bias (log2 domain): sv[kvt*4+reg], kv = c*32 + kvt*16 + g*4 + reg
    float sv[8];
    if (USE_BT) {
#pragma unroll
      for (int kvt = 0; kvt < 2; ++kvt)
#pragma unroll
        for (int p = 0; p < 2; ++p) {
          const _Float16* hp = (const _Float16*)&bw[kvt * 2 + p];
          const int i = kvt * 4 + 2 * p;
          const float* sp = (kvt == 0) ? (const float*)&s0 : (const float*)&s1;
          sv[i] = fmaf(sp[2 * p], scale2, (float)hp[0]);
          sv[i + 1] = fmaf(sp[2 * p + 1], scale2, (float)hp[1]);
        }
    } else {
#pragma unroll
      for (int i = 0; i < 4; ++i) sv[i] = fmaf(s0[i], scale2, bvf[i]);
#pragma unroll
      for (int i = 0; i < 4; ++i) sv[4 + i] = fmaf(s1[i], scale2, bvf[4 + i]);
    }

    // tree max + cross-group reduce
    float m4[4];
#pragma unroll
    for (int i = 0; i < 4; ++i) m4[i] = fmaxf(sv[2 * i], sv[2 * i + 1]);
    float mx = fmaxf(fmaxf(m4[0], m4[1]), fmaxf(m4[2], m4[3]));
    mx = fmaxf(mx, __shfl_xor(mx, 16));
    mx = fmaxf(mx, __shfl_xor(mx, 32));

    // defer-max: rescale only when running max grows by > 8 (log2)
    if (__any(mx > m + 8.0f)) {
      const float mnew = fmaxf(m, mx);
      const float corr = exp2f(m - mnew);
      lsum *= corr;
#pragma unroll
      for (int dt = 0; dt < 4; ++dt)
#pragma unroll
        for (int i = 0; i < 4; ++i) o[dt][i] *= corr;
      m = mnew;
    }

    // exp2 + tree psum
#pragma unroll
    for (int i = 0; i < 8; ++i) sv[i] = exp2f(sv[i] - m);
    float a4[4];
#pragma unroll
    for (int i = 0; i < 4; ++i) a4[i] = sv[2 * i] + sv[2 * i + 1];
    float psum = (a4[0] + a4[1]) + (a4[2] + a4[3]);
    psum += __shfl_xor(psum, 16);
    psum += __shfl_xor(psum, 32);
    lsum += psum;

    // pack P -> PV B-frag directly (permuted-k: slot j holds kv = c*32+16*(j>>2)+4g+(j&3))
    union { unsigned u[4]; half8 hh; } pf;
    pf.u[0] = __builtin_bit_cast(unsigned, __builtin_amdgcn_cvt_pkrtz(sv[0], sv[1]));
    pf.u[1] = __builtin_bit_cast(unsigned, __builtin_amdgcn_cvt_pkrtz(sv[2], sv[3]));
    pf.u[2] = __builtin_bit_cast(unsigned, __builtin_amdgcn_cvt_pkrtz(sv[4], sv[5]));
    pf.u[3] = __builtin_bit_cast(unsigned, __builtin_amdgcn_cvt_pkrtz(sv[6], sv[7]));

    // PV (16x16x32, permuted k): o[dt] += Vt'[d][c*32+8g .. +7] * pf
#pragma unroll
    for (int dt = 0; dt < 4; ++dt) {
      const int d = dt * 16 + q16;
      const char* vb = VtB + d * 512;
      const half8 vf = *(const half8*)(vb + ((c * 64 + g * 16) ^ ((d & 31) << 4)));
      o[dt] = __builtin_amdgcn_mfma_f32_16x16x32_f16(vf, pf.hh, o[dt], 0, 0, 0);
    }
  }

  __syncthreads();  // all waves done with Kn/Vt; reuse smem for epilogue

  // ---- epilogue: per-wave fp16 LDS [16 q][64 d] (2 KB) -> coalesced stores ----
  // swizzle: byte ^= (q&15)<<3 (8B granule)
  char* ob = smem + wv * 2048;
  const float invl = 1.0f / lsum;
#pragma unroll
  for (int dt = 0; dt < 4; ++dt) {
    uint2 w;
    w.x = __builtin_bit_cast(unsigned,
        __builtin_amdgcn_cvt_pkrtz(o[dt][0] * invl, o[dt][1] * invl));
    w.y = __builtin_bit_cast(unsigned,
        __builtin_amdgcn_cvt_pkrtz(o[dt][2] * invl, o[dt][3] * invl));
    *(uint2*)(ob + q16 * 128 + ((dt * 32 + g * 8) ^ (q16 << 3))) = w;
  }
  __asm__ __volatile__("s_waitcnt lgkmcnt(0)" ::: "memory");
  __builtin_amdgcn_sched_barrier(0);
  const int qr = lane >> 2;  // 0..15
  const int fc = lane & 3;
#pragma unroll
  for (int it = 0; it < 4; ++it) {
    const int s4 = fc + it * 4;  // float4 slot -> d = s4*4
    union { uint2 u; _Float16 hh[4]; } rd4;
    rd4.u = *(const uint2*)(ob + qr * 128 + ((s4 * 8) ^ (qr << 3)));
    float4 val;
    val.x = (float)rd4.hh[0];
    val.y = (float)rd4.hh[1];
    val.z = (float)rd4.hh[2];
    val.w = (float)rd4.hh[3];
    *(float4*)(out + (((long)(b * 256 + wv * 16 + qr) * 8 + head) * 64 + s4 * 4)) = val;
  }
}

extern "C" void kernel_launch(void* const* d_in, const int* in_sizes, int n_in,
                              void* d_out, int out_size, void* d_ws, size_t ws_size,
                              hipStream_t stream) {
  (void)in_sizes; (void)n_in; (void)out_size;
  const float* q = (const float*)d_in[0];
  const float* k = (const float*)d_in[1];
  const float* v = (const float*)d_in[2];
  const float* ls = (const float*)d_in[3];
  const float* bias = (const float*)d_in[4];
  float* out = (float*)d_out;
  const size_t bpBytes = (size_t)8 * 128 * 256 * 4;  // 1 MB
  if (ws_size >= bpBytes) {
    unsigned* biasP = (unsigned*)d_ws;
    bias_pack<<<dim3(8, 8, 8), dim3(32, 8), 0, stream>>>(bias, biasP);
    attn_kernel<true><<<dim3(8, 256), dim3(1024), 0, stream>>>(q, k, v, ls, bias, biasP, out);
  } else {
    attn_kernel<false><<<dim3(8, 256), dim3(1024), 0, stream>>>(q, k, v, ls, bias, nullptr, out);
  }
}